// Round 6
// baseline (449.217 us; speedup 1.0000x reference)
//
#include <hip/hip_runtime.h>
#include <hip/hip_bf16.h>

typedef __attribute__((ext_vector_type(8))) short short8;
typedef __attribute__((ext_vector_type(4))) float floatx4;
typedef __attribute__((ext_vector_type(16))) float floatx16;

#define LN_EPS 1e-5f
// exp(score/8) = exp2(score * 0.125 * log2(e)); folded into Q at QKV epilogue
#define EXP2_SCALE 0.18033688011112042f

__device__ __forceinline__ float b2f(unsigned short u) {
    union { float f; unsigned int i; } x; x.i = ((unsigned int)u) << 16; return x.f;
}
__device__ __forceinline__ unsigned short f2b(float f) {
    union { float f; unsigned int i; } x; x.f = f;
    unsigned int r = x.i + 0x7fffu + ((x.i >> 16) & 1u);
    return (unsigned short)(r >> 16);
}
__device__ __forceinline__ float to_f(unsigned short u) { return b2f(u); }
__device__ __forceinline__ float to_f(float f) { return f; }
__device__ __forceinline__ unsigned int pk_bf16(float a, float b) {
    union { float f; unsigned int i; } xa, xb; xa.f = a; xb.f = b;
    return (xa.i >> 16) | (xb.i & 0xffff0000u);
}

// async global->LDS, 16B/lane. LDS dest = wave-uniform base + lane*16 (per-lane global addr OK).
__device__ __forceinline__ void async16(const unsigned short* g, unsigned short* l) {
    __builtin_amdgcn_global_load_lds(
        (const __attribute__((address_space(1))) unsigned int*)g,
        (__attribute__((address_space(3))) unsigned int*)l, 16, 0, 0);
}

// ---------------- fused fp32->bf16 conversion of all 6 weights ----------------
__global__ __launch_bounds__(256)
void cvt_all(const float* __restrict__ Wq, const float* __restrict__ Wk,
             const float* __restrict__ Wv, const float* __restrict__ Wo,
             const float* __restrict__ W1, const float* __restrict__ W2,
             unsigned short* __restrict__ dst)
{
    const size_t i = (size_t)(blockIdx.x * 256 + threadIdx.x) * 8;
    const float* src; size_t off;
    if (i < 4194304) {
        int w = (int)(i >> 20);
        src = (w == 0) ? Wq : (w == 1) ? Wk : (w == 2) ? Wv : Wo;
        off = i & 1048575;
    } else if (i < 8388608) { src = W1; off = i - 4194304; }
    else                    { src = W2; off = i - 8388608; }
    float4 a = *reinterpret_cast<const float4*>(src + off);
    float4 b = *reinterpret_cast<const float4*>(src + off + 4);
    short8 r;
    r[0] = (short)f2b(a.x); r[1] = (short)f2b(a.y);
    r[2] = (short)f2b(a.z); r[3] = (short)f2b(a.w);
    r[4] = (short)f2b(b.x); r[5] = (short)f2b(b.y);
    r[6] = (short)f2b(b.z); r[7] = (short)f2b(b.w);
    *reinterpret_cast<short8*>(dst + i) = r;
}

// ---------------- LayerNorm: T in (fp32 or bf16), bf16 out ----------------
template<typename T>
__global__ __launch_bounds__(256)
void ln_kernel(const T* __restrict__ x, const float* __restrict__ g,
               const float* __restrict__ bb, unsigned short* __restrict__ out)
{
    __shared__ float red[8];
    const int row = blockIdx.x, tid = threadIdx.x;
    const T* xr = x + (size_t)row * 1024;
    float v[4];
#pragma unroll
    for (int i = 0; i < 4; i++) v[i] = to_f(xr[tid + i * 256]);
    float s  = v[0] + v[1] + v[2] + v[3];
    float sq = v[0]*v[0] + v[1]*v[1] + v[2]*v[2] + v[3]*v[3];
#pragma unroll
    for (int o = 32; o >= 1; o >>= 1) {
        s  += __shfl_xor(s,  o, 64);
        sq += __shfl_xor(sq, o, 64);
    }
    const int wave = tid >> 6, lane = tid & 63;
    if (lane == 0) { red[wave] = s; red[4 + wave] = sq; }
    __syncthreads();
    s  = red[0] + red[1] + red[2] + red[3];
    sq = red[4] + red[5] + red[6] + red[7];
    const float mu  = s * (1.0f / 1024.0f);
    const float var = sq * (1.0f / 1024.0f) - mu * mu;
    const float rs  = rsqrtf(var + LN_EPS);
#pragma unroll
    for (int i = 0; i < 4; i++) {
        int c = tid + i * 256;
        float o = (v[i] - mu) * rs * g[c] + bb[c];
        out[(size_t)row * 1024 + c] = f2b(o);
    }
}

// ================= GEMM core: 32x32x16 MFMA, BK=64, XOR-swizzled [128][64] LDS =================
// Wave tile 64x64 = 2x2 of 32x32. A/B frag: row=lane&31, k=(lane>>5)*8+j.
// C/D: col=lane&31, row=(reg&3)+8*(reg>>2)+4*(lane>>5)  [m74/m101 verified]
// EPI 1: bf16 out = acc + bias + fp32 residual   (Wo -> x1b)
// EPI 2: fp32 out = acc + bias + bf16 residual   (W2 -> final out)
template<int EPI>
__global__ __launch_bounds__(256, 4)
void gemm_nt(const unsigned short* __restrict__ A, const unsigned short* __restrict__ B,
             const float* __restrict__ bias, const void* __restrict__ res,
             void* __restrict__ C, int M, int N, int K)
{
    __shared__ unsigned short As[128 * 64];
    __shared__ unsigned short Bs[128 * 64];
    const int m0 = blockIdx.y * 128, n0 = blockIdx.x * 128;
    const int tid = threadIdx.x, wave = tid >> 6, lane = tid & 63;
    const int wm = (wave >> 1) * 64, wn = (wave & 1) * 64;
    const int l32 = lane & 31, half = lane >> 5;
    const int srow = wave * 32 + (lane >> 3);
    const int scol = (((lane & 7) ^ ((lane >> 3) & 7)) << 3);

    floatx16 acc[2][2] = {};
    const unsigned short* gA = A + (size_t)(m0 + srow) * K + scol;
    const unsigned short* gB = B + (size_t)(n0 + srow) * K + scol;
    unsigned short* lA = &As[(wave * 32) * 64];
    unsigned short* lB = &Bs[(wave * 32) * 64];

    for (int k0 = 0; k0 < K; k0 += 64) {
        __syncthreads();
#pragma unroll
        for (int r = 0; r < 4; r++) {
            async16(gA + k0 + (size_t)(r * 8) * K, lA + r * 8 * 64);
            async16(gB + k0 + (size_t)(r * 8) * K, lB + r * 8 * 64);
        }
        __syncthreads();
#pragma unroll
        for (int s = 0; s < 4; s++) {
            const int ca = (((2 * s + half) ^ (l32 & 7)) << 3);
            short8 af[2], bf[2];
#pragma unroll
            for (int i = 0; i < 2; i++)
                af[i] = *reinterpret_cast<const short8*>(&As[(wm + i * 32 + l32) * 64 + ca]);
#pragma unroll
            for (int j = 0; j < 2; j++)
                bf[j] = *reinterpret_cast<const short8*>(&Bs[(wn + j * 32 + l32) * 64 + ca]);
#pragma unroll
            for (int i = 0; i < 2; i++)
#pragma unroll
                for (int j = 0; j < 2; j++)
                    acc[i][j] = __builtin_amdgcn_mfma_f32_32x32x16_bf16(af[i], bf[j], acc[i][j], 0, 0, 0);
        }
    }

#pragma unroll
    for (int i = 0; i < 2; i++) {
#pragma unroll
        for (int j = 0; j < 2; j++) {
            int col = n0 + wn + j * 32 + l32;
            float bv = bias[col];
#pragma unroll
            for (int g = 0; g < 4; g++) {
                int row = m0 + wm + i * 32 + g * 8 + half * 4;
#pragma unroll
                for (int q = 0; q < 4; q++) {
                    size_t idx = (size_t)(row + q) * N + col;
                    float v = acc[i][j][g * 4 + q] + bv;
                    if (EPI == 1) {
                        v += ((const float*)res)[idx];
                        ((unsigned short*)C)[idx] = f2b(v);
                    } else {
                        v += b2f(((const unsigned short*)res)[idx]);
                        ((float*)C)[idx] = v;
                    }
                }
            }
        }
    }
}

// ---------------- fused QKV (32x32x16); Q pre-scaled; V -> per-head transposed Vt ----------------
__global__ __launch_bounds__(256, 4)
void gemm_qkv(const unsigned short* __restrict__ A, const unsigned short* __restrict__ Wqkv,
              const float* __restrict__ bq, const float* __restrict__ bk, const float* __restrict__ bv,
              unsigned short* __restrict__ QK, unsigned short* __restrict__ Vt)
{
    __shared__ unsigned short As[128 * 64];
    __shared__ unsigned short Bs[128 * 64];
    const int part = blockIdx.x >> 3;            // 0=Q 1=K 2=V
    const int m0 = blockIdx.y * 128, n0 = (blockIdx.x & 7) * 128;
    const int tid = threadIdx.x, wave = tid >> 6, lane = tid & 63;
    const int wm = (wave >> 1) * 64, wn = (wave & 1) * 64;
    const int l32 = lane & 31, half = lane >> 5;
    const int srow = wave * 32 + (lane >> 3);
    const int scol = (((lane & 7) ^ ((lane >> 3) & 7)) << 3);
    const unsigned short* B = Wqkv + (size_t)part * 1048576;
    const float* bias = (part == 0) ? bq : (part == 1) ? bk : bv;

    floatx16 acc[2][2] = {};
    const unsigned short* gA = A + (size_t)(m0 + srow) * 1024 + scol;
    const unsigned short* gB = B + (size_t)(n0 + srow) * 1024 + scol;
    unsigned short* lA = &As[(wave * 32) * 64];
    unsigned short* lB = &Bs[(wave * 32) * 64];

    for (int k0 = 0; k0 < 1024; k0 += 64) {
        __syncthreads();
#pragma unroll
        for (int r = 0; r < 4; r++) {
            async16(gA + k0 + (size_t)(r * 8) * 1024, lA + r * 8 * 64);
            async16(gB + k0 + (size_t)(r * 8) * 1024, lB + r * 8 * 64);
        }
        __syncthreads();
#pragma unroll
        for (int s = 0; s < 4; s++) {
            const int ca = (((2 * s + half) ^ (l32 & 7)) << 3);
            short8 af[2], bf[2];
#pragma unroll
            for (int i = 0; i < 2; i++)
                af[i] = *reinterpret_cast<const short8*>(&As[(wm + i * 32 + l32) * 64 + ca]);
#pragma unroll
            for (int j = 0; j < 2; j++)
                bf[j] = *reinterpret_cast<const short8*>(&Bs[(wn + j * 32 + l32) * 64 + ca]);
#pragma unroll
            for (int i = 0; i < 2; i++)
#pragma unroll
                for (int j = 0; j < 2; j++)
                    acc[i][j] = __builtin_amdgcn_mfma_f32_32x32x16_bf16(af[i], bf[j], acc[i][j], 0, 0, 0);
        }
    }

#pragma unroll
    for (int i = 0; i < 2; i++) {
#pragma unroll
        for (int j = 0; j < 2; j++) {
            int col = n0 + wn + j * 32 + l32;
            float bv2 = bias[col];
            if (part == 0) {
#pragma unroll
                for (int g = 0; g < 4; g++) {
                    int row = m0 + wm + i * 32 + g * 8 + half * 4;
#pragma unroll
                    for (int q = 0; q < 4; q++)
                        QK[(size_t)(row + q) * 1024 + col] = f2b((acc[i][j][g * 4 + q] + bv2) * EXP2_SCALE);
                }
            } else if (part == 1) {
                unsigned short* dst = QK + 8388608;
#pragma unroll
                for (int g = 0; g < 4; g++) {
                    int row = m0 + wm + i * 32 + g * 8 + half * 4;
#pragma unroll
                    for (int q = 0; q < 4; q++)
                        dst[(size_t)(row + q) * 1024 + col] = f2b(acc[i][j][g * 4 + q] + bv2);
                }
            } else {
                int h = col >> 6, d = col & 63;
#pragma unroll
                for (int g = 0; g < 4; g++) {
                    int row = m0 + wm + i * 32 + g * 8 + half * 4;   // 4 consecutive tokens
                    int b = row >> 11, spos = row & 2047;
                    unsigned short* dst = Vt + (((size_t)(b * 16 + h) * 64 + d) << 11) + spos;
                    unsigned int u01 = pk_bf16(acc[i][j][g * 4 + 0] + bv2, acc[i][j][g * 4 + 1] + bv2);
                    unsigned int u23 = pk_bf16(acc[i][j][g * 4 + 2] + bv2, acc[i][j][g * 4 + 3] + bv2);
                    *reinterpret_cast<uint2*>(dst) = make_uint2(u01, u23);
                }
            }
        }
    }
}

// ---------------- Fused W1 + ReGLU (32x32x16) ----------------
__global__ __launch_bounds__(256, 3)
void gemm_w1_reglu(const unsigned short* __restrict__ A, const unsigned short* __restrict__ B,
                   const float* __restrict__ bias, unsigned short* __restrict__ G)
{
    __shared__ unsigned short As[128 * 64];
    __shared__ unsigned short B0s[128 * 64];
    __shared__ unsigned short B1s[128 * 64];
    const int m0 = blockIdx.y * 128, n0 = blockIdx.x * 128;  // n0 in [0,2048)
    const int tid = threadIdx.x, wave = tid >> 6, lane = tid & 63;
    const int wm = (wave >> 1) * 64, wn = (wave & 1) * 64;
    const int l32 = lane & 31, half = lane >> 5;
    const int srow = wave * 32 + (lane >> 3);
    const int scol = (((lane & 7) ^ ((lane >> 3) & 7)) << 3);

    floatx16 acca[2][2] = {};
    floatx16 accb[2][2] = {};
    const unsigned short* gA  = A + (size_t)(m0 + srow) * 1024 + scol;
    const unsigned short* gB0 = B + (size_t)(n0 + srow) * 1024 + scol;
    const unsigned short* gB1 = B + (size_t)(2048 + n0 + srow) * 1024 + scol;
    unsigned short* lA  = &As [(wave * 32) * 64];
    unsigned short* lB0 = &B0s[(wave * 32) * 64];
    unsigned short* lB1 = &B1s[(wave * 32) * 64];

    for (int k0 = 0; k0 < 1024; k0 += 64) {
        __syncthreads();
#pragma unroll
        for (int r = 0; r < 4; r++) {
            async16(gA  + k0 + (size_t)(r * 8) * 1024, lA  + r * 8 * 64);
            async16(gB0 + k0 + (size_t)(r * 8) * 1024, lB0 + r * 8 * 64);
            async16(gB1 + k0 + (size_t)(r * 8) * 1024, lB1 + r * 8 * 64);
        }
        __syncthreads();
#pragma unroll
        for (int s = 0; s < 4; s++) {
            const int ca = (((2 * s + half) ^ (l32 & 7)) << 3);
            short8 af[2], b0[2], b1[2];
#pragma unroll
            for (int i = 0; i < 2; i++)
                af[i] = *reinterpret_cast<const short8*>(&As[(wm + i * 32 + l32) * 64 + ca]);
#pragma unroll
            for (int j = 0; j < 2; j++) {
                b0[j] = *reinterpret_cast<const short8*>(&B0s[(wn + j * 32 + l32) * 64 + ca]);
                b1[j] = *reinterpret_cast<const short8*>(&B1s[(wn + j * 32 + l32) * 64 + ca]);
            }
#pragma unroll
            for (int i = 0; i < 2; i++)
#pragma unroll
                for (int j = 0; j < 2; j++) {
                    acca[i][j] = __builtin_amdgcn_mfma_f32_32x32x16_bf16(af[i], b0[j], acca[i][j], 0, 0, 0);
                    accb[i][j] = __builtin_amdgcn_mfma_f32_32x32x16_bf16(af[i], b1[j], accb[i][j], 0, 0, 0);
                }
        }
    }

#pragma unroll
    for (int i = 0; i < 2; i++) {
#pragma unroll
        for (int j = 0; j < 2; j++) {
            int col = n0 + wn + j * 32 + l32;
            float ba = bias[col], bb2 = bias[2048 + col];
#pragma unroll
            for (int g = 0; g < 4; g++) {
                int row = m0 + wm + i * 32 + g * 8 + half * 4;
#pragma unroll
                for (int q = 0; q < 4; q++) {
                    float va = acca[i][j][g * 4 + q] + ba;
                    float vb = accb[i][j][g * 4 + q] + bb2;
                    G[(size_t)(row + q) * 2048 + col] = f2b(fmaxf(va, 0.0f) * vb);
                }
            }
        }
    }
}

// ---------------- Flash attention: S^T layout (swapped QK operands), unchanged from R5 ----------------
__global__ __launch_bounds__(256, 3)
void attn_kernel(const unsigned short* __restrict__ Qm, const unsigned short* __restrict__ Km,
                 const unsigned short* __restrict__ Vt, unsigned short* __restrict__ ctx)
{
    __shared__ unsigned short Ks[64 * 64];      // [key][d], chunk-swizzled
    __shared__ unsigned short Vs[64 * 64];      // [d][key], chunk-swizzled
    __shared__ unsigned short Ps[4][32][72];    // per-wave P tile [qrow][key], padded

    const int tid = threadIdx.x, wave = tid >> 6, lane = tid & 63;
    const int lrow = lane & 15, quad = lane >> 4;
    const int qb = blockIdx.x, bh = blockIdx.y;
    const size_t base  = (size_t)(bh >> 4) * 2048 * 1024 + (size_t)(bh & 15) * 64;
    const size_t vbase = (size_t)bh * 131072;   // Vt head base [d][2048]
    const int q0 = qb * 128 + wave * 32;
    const int g_sub = (lane >> 3);
    const int g_col = (((lane & 7) ^ (g_sub & 7)) << 3);
    const int ca0 = (quad ^ (lrow & 7)) << 3;
    const int ca1 = ((quad + 4) ^ (lrow & 7)) << 3;

    short8 qf[2][2];
#pragma unroll
    for (int m = 0; m < 2; m++) {
        const unsigned short* qp = Qm + base + (size_t)(q0 + m * 16 + lrow) * 1024 + quad * 8;
        qf[m][0] = *reinterpret_cast<const short8*>(qp);
        qf[m][1] = *reinterpret_cast<const short8*>(qp + 32);
    }

    floatx4 o[2][4] = {};
    float li[2] = {0.f, 0.f};

    for (int t = 0; t < 32; t++) {
        const int k0 = t * 64;
        __syncthreads();
#pragma unroll
        for (int r = 0; r < 2; r++) {
            int krow = wave * 16 + r * 8 + g_sub;
            async16(Km + base + (size_t)(k0 + krow) * 1024 + g_col, &Ks[(wave * 16 + r * 8) * 64]);
            async16(Vt + vbase + (size_t)krow * 2048 + k0 + g_col,  &Vs[(wave * 16 + r * 8) * 64]);
        }
        __syncthreads();

        short8 kf0[4], kf1[4];
#pragma unroll
        for (int j = 0; j < 4; j++) {
            kf0[j] = *reinterpret_cast<const short8*>(&Ks[(j * 16 + lrow) * 64 + ca0]);
            kf1[j] = *reinterpret_cast<const short8*>(&Ks[(j * 16 + lrow) * 64 + ca1]);
        }
        floatx4 s4t[2][4] = {};
#pragma unroll
        for (int m = 0; m < 2; m++)
#pragma unroll
            for (int j = 0; j < 4; j++) {
                s4t[m][j] = __builtin_amdgcn_mfma_f32_16x16x32_bf16(kf0[j], qf[m][0], s4t[m][j], 0, 0, 0);
                s4t[m][j] = __builtin_amdgcn_mfma_f32_16x16x32_bf16(kf1[j], qf[m][1], s4t[m][j], 0, 0, 0);
            }

#pragma unroll
        for (int m = 0; m < 2; m++) {
            float acc = 0.f;
#pragma unroll
            for (int j = 0; j < 4; j++) {
                float p0 = __builtin_amdgcn_exp2f(s4t[m][j][0]);
                float p1 = __builtin_amdgcn_exp2f(s4t[m][j][1]);
                float p2 = __builtin_amdgcn_exp2f(s4t[m][j][2]);
                float p3 = __builtin_amdgcn_exp2f(s4t[m][j][3]);
                acc += (p0 + p1) + (p2 + p3);
                uint2 pk = make_uint2(pk_bf16(p0, p1), pk_bf16(p2, p3));
                *reinterpret_cast<uint2*>(&Ps[wave][m * 16 + lrow][j * 16 + quad * 4]) = pk;
            }
            li[m] += acc;
        }
        __asm__ volatile("s_waitcnt lgkmcnt(0)" ::: "memory");

        short8 pf[2][2];
#pragma unroll
        for (int m = 0; m < 2; m++) {
            pf[m][0] = *reinterpret_cast<const short8*>(&Ps[wave][m * 16 + lrow][quad * 8]);
            pf[m][1] = *reinterpret_cast<const short8*>(&Ps[wave][m * 16 + lrow][32 + quad * 8]);
        }
#pragma unroll
        for (int jj = 0; jj < 4; jj++) {
            short8 vf0 = *reinterpret_cast<const short8*>(&Vs[(jj * 16 + lrow) * 64 + ca0]);
            short8 vf1 = *reinterpret_cast<const short8*>(&Vs[(jj * 16 + lrow) * 64 + ca1]);
#pragma unroll
            for (int m = 0; m < 2; m++) {
                o[m][jj] = __builtin_amdgcn_mfma_f32_16x16x32_bf16(pf[m][0], vf0, o[m][jj], 0, 0, 0);
                o[m][jj] = __builtin_amdgcn_mfma_f32_16x16x32_bf16(pf[m][1], vf1, o[m][jj], 0, 0, 0);
            }
        }
    }

#pragma unroll
    for (int m = 0; m < 2; m++) {
        float l = li[m];
        l += __shfl_xor(l, 16, 64);
        l += __shfl_xor(l, 32, 64);
        float inv = 1.0f / l;
#pragma unroll
        for (int r = 0; r < 4; r++) {
            float invr = __shfl(inv, quad * 4 + r, 64);
            int srow = q0 + m * 16 + quad * 4 + r;
#pragma unroll
            for (int jj = 0; jj < 4; jj++)
                ctx[base + (size_t)srow * 1024 + jj * 16 + lrow] = f2b(o[m][jj][r] * invr);
        }
    }
}

extern "C" void kernel_launch(void* const* d_in, const int* in_sizes, int n_in,
                              void* d_out, int out_size, void* d_ws, size_t ws_size,
                              hipStream_t stream) {
    const float* x    = (const float*)d_in[0];
    const float* Wq   = (const float*)d_in[1];
    const float* bq   = (const float*)d_in[2];
    const float* Wk   = (const float*)d_in[3];
    const float* bk   = (const float*)d_in[4];
    const float* Wv   = (const float*)d_in[5];
    const float* bv   = (const float*)d_in[6];
    const float* Wo   = (const float*)d_in[7];
    const float* bo   = (const float*)d_in[8];
    const float* ln1g = (const float*)d_in[9];
    const float* ln1b = (const float*)d_in[10];
    const float* ln2g = (const float*)d_in[11];
    const float* ln2b = (const float*)d_in[12];
    const float* W1   = (const float*)d_in[13];
    const float* b1   = (const float*)d_in[14];
    const float* W2   = (const float*)d_in[15];
    const float* b2   = (const float*)d_in[16];
    float* out = (float*)d_out;

    char* ws = (char*)d_ws;
    // Workspace (100 MB peak):
    // [0,20MB)   bf16 weights flat: wq wk wv wo w1 w2
    // [20,36MB)  xn -> ctx -> xn2 (bf16 8192x1024)
    // [36,52MB)  Q   -> x1b (bf16 residual after attention)
    // [52,68MB)  K
    // [68,84MB)  Vt  }  g (bf16 8192x2048) overlays [68,100)
    unsigned short* wflat = (unsigned short*)ws;
    unsigned short* wqb = wflat;
    unsigned short* wob = wflat + 3145728;
    unsigned short* w1b = wflat + 4194304;
    unsigned short* w2b = wflat + 8388608;
    unsigned short* xn  = (unsigned short*)(ws + 20971520);
    unsigned short* Qm  = (unsigned short*)(ws + 37748736);
    unsigned short* x1b = (unsigned short*)(ws + 37748736);
    unsigned short* Vt  = (unsigned short*)(ws + 71303168);
    unsigned short* g   = (unsigned short*)(ws + 71303168);

    dim3 blk(256);
    cvt_all<<<5120, blk, 0, stream>>>(Wq, Wk, Wv, Wo, W1, W2, wflat);
    ln_kernel<float><<<8192, blk, 0, stream>>>(x, ln1g, ln1b, xn);
    gemm_qkv<<<dim3(24, 64), blk, 0, stream>>>(xn, wqb, bq, bk, bv, Qm, Vt);
    attn_kernel<<<dim3(16, 64), blk, 0, stream>>>(Qm, Qm + 8388608, Vt, xn);
    // Wo + residual(x fp32) -> x1b (bf16, overwrites Q region)
    gemm_nt<1><<<dim3(8, 64), blk, 0, stream>>>(xn, wob, bo, x, x1b, 8192, 1024, 1024);
    ln_kernel<unsigned short><<<8192, blk, 0, stream>>>(x1b, ln2g, ln2b, xn);
    gemm_w1_reglu<<<dim3(16, 64), blk, 0, stream>>>(xn, w1b, b1, g);
    // W2 + residual(x1b bf16) -> out fp32
    gemm_nt<2><<<dim3(8, 64), blk, 0, stream>>>(g, w2b, b2, x1b, out, 8192, 1024, 2048);
}

// Round 7
// 411.292 us; speedup vs baseline: 1.0922x; 1.0922x over previous
//
#include <hip/hip_runtime.h>
#include <hip/hip_bf16.h>

typedef __attribute__((ext_vector_type(8))) short short8;
typedef __attribute__((ext_vector_type(4))) float floatx4;

#define LN_EPS 1e-5f
// exp(score/8) = exp2(score * 0.125 * log2(e)); folded into Q at QKV epilogue
#define EXP2_SCALE 0.18033688011112042f

__device__ __forceinline__ float b2f(unsigned short u) {
    union { float f; unsigned int i; } x; x.i = ((unsigned int)u) << 16; return x.f;
}
__device__ __forceinline__ unsigned short f2b(float f) {
    union { float f; unsigned int i; } x; x.f = f;
    unsigned int r = x.i + 0x7fffu + ((x.i >> 16) & 1u);
    return (unsigned short)(r >> 16);
}
__device__ __forceinline__ float to_f(unsigned short u) { return b2f(u); }
__device__ __forceinline__ float to_f(float f) { return f; }
__device__ __forceinline__ unsigned int pk_bf16(float a, float b) {
    union { float f; unsigned int i; } xa, xb; xa.f = a; xb.f = b;
    return (xa.i >> 16) | (xb.i & 0xffff0000u);
}

// async global->LDS, 16B/lane. LDS dest = wave-uniform base + lane*16 (per-lane global addr OK).
__device__ __forceinline__ void async16(const unsigned short* g, unsigned short* l) {
    __builtin_amdgcn_global_load_lds(
        (const __attribute__((address_space(1))) unsigned int*)g,
        (__attribute__((address_space(3))) unsigned int*)l, 16, 0, 0);
}

// ---------------- shared LN row routine (one block = one row of 1024) ----------------
template<typename T>
__device__ __forceinline__ void ln_row(const T* __restrict__ xr, const float* __restrict__ g,
                                       const float* __restrict__ bb, unsigned short* __restrict__ outr,
                                       float* red)
{
    const int tid = threadIdx.x;
    float v[4];
#pragma unroll
    for (int i = 0; i < 4; i++) v[i] = to_f(xr[tid + i * 256]);
    float s  = v[0] + v[1] + v[2] + v[3];
    float sq = v[0]*v[0] + v[1]*v[1] + v[2]*v[2] + v[3]*v[3];
#pragma unroll
    for (int o = 32; o >= 1; o >>= 1) {
        s  += __shfl_xor(s,  o, 64);
        sq += __shfl_xor(sq, o, 64);
    }
    const int wave = tid >> 6, lane = tid & 63;
    if (lane == 0) { red[wave] = s; red[4 + wave] = sq; }
    __syncthreads();
    s  = red[0] + red[1] + red[2] + red[3];
    sq = red[4] + red[5] + red[6] + red[7];
    const float mu  = s * (1.0f / 1024.0f);
    const float var = sq * (1.0f / 1024.0f) - mu * mu;
    const float rs  = rsqrtf(var + LN_EPS);
#pragma unroll
    for (int i = 0; i < 4; i++) {
        int c = tid + i * 256;
        outr[c] = f2b((v[i] - mu) * rs * g[c] + bb[c]);
    }
}

// ---------------- prep: blocks [0,5120) cvt weights; [5120,13312) LN1 rows ----------------
__global__ __launch_bounds__(256)
void prep_kernel(const float* __restrict__ Wq, const float* __restrict__ Wk,
                 const float* __restrict__ Wv, const float* __restrict__ Wo,
                 const float* __restrict__ W1, const float* __restrict__ W2,
                 unsigned short* __restrict__ wdst,
                 const float* __restrict__ x, const float* __restrict__ ln1g,
                 const float* __restrict__ ln1b, unsigned short* __restrict__ xn)
{
    __shared__ float red[8];
    if (blockIdx.x < 5120) {
        const size_t i = (size_t)(blockIdx.x * 256 + threadIdx.x) * 8;
        const float* src; size_t off;
        if (i < 4194304) {
            int w = (int)(i >> 20);
            src = (w == 0) ? Wq : (w == 1) ? Wk : (w == 2) ? Wv : Wo;
            off = i & 1048575;
        } else if (i < 8388608) { src = W1; off = i - 4194304; }
        else                    { src = W2; off = i - 8388608; }
        float4 a = *reinterpret_cast<const float4*>(src + off);
        float4 b = *reinterpret_cast<const float4*>(src + off + 4);
        short8 r;
        r[0] = (short)f2b(a.x); r[1] = (short)f2b(a.y);
        r[2] = (short)f2b(a.z); r[3] = (short)f2b(a.w);
        r[4] = (short)f2b(b.x); r[5] = (short)f2b(b.y);
        r[6] = (short)f2b(b.z); r[7] = (short)f2b(b.w);
        *reinterpret_cast<short8*>(wdst + i) = r;
    } else {
        const int row = blockIdx.x - 5120;
        ln_row<float>(x + (size_t)row * 1024, ln1g, ln1b, xn + (size_t)row * 1024, red);
    }
}

// ---------------- standalone LN (for LN2, bf16 in) ----------------
__global__ __launch_bounds__(256)
void ln_kernel(const unsigned short* __restrict__ x, const float* __restrict__ g,
               const float* __restrict__ bb, unsigned short* __restrict__ out)
{
    __shared__ float red[8];
    const int row = blockIdx.x;
    ln_row<unsigned short>(x + (size_t)row * 1024, g, bb, out + (size_t)row * 1024, red);
}

// ================= GEMM core: 16x16x32 MFMA, BK=64, XOR-swizzled [128][64] LDS =================
// EPI 1: bf16 out = acc + bias + fp32 residual   (Wo -> x1b)
// EPI 2: fp32 out = acc + bias + bf16 residual   (W2 -> final out)
template<int EPI>
__global__ __launch_bounds__(256, 3)
void gemm_nt(const unsigned short* __restrict__ A, const unsigned short* __restrict__ B,
             const float* __restrict__ bias, const void* __restrict__ res,
             void* __restrict__ C, int M, int N, int K)
{
    __shared__ unsigned short As[128 * 64];
    __shared__ unsigned short Bs[128 * 64];
    const int m0 = blockIdx.y * 128, n0 = blockIdx.x * 128;
    const int tid = threadIdx.x, wave = tid >> 6, lane = tid & 63;
    const int wm = (wave >> 1) * 64, wn = (wave & 1) * 64;
    const int lrow = lane & 15, quad = lane >> 4;
    const int srow = wave * 32 + (lane >> 3);
    const int scol = (((lane & 7) ^ ((lane >> 3) & 7)) << 3);
    const int ca0 = (quad ^ (lrow & 7)) << 3;
    const int ca1 = ((quad + 4) ^ (lrow & 7)) << 3;

    floatx4 acc[4][4] = {};
    const unsigned short* gA = A + (size_t)(m0 + srow) * K + scol;
    const unsigned short* gB = B + (size_t)(n0 + srow) * K + scol;
    unsigned short* lA = &As[(wave * 32) * 64];
    unsigned short* lB = &Bs[(wave * 32) * 64];

    for (int k0 = 0; k0 < K; k0 += 64) {
        __syncthreads();
#pragma unroll
        for (int r = 0; r < 4; r++) {
            async16(gA + k0 + (size_t)(r * 8) * K, lA + r * 8 * 64);
            async16(gB + k0 + (size_t)(r * 8) * K, lB + r * 8 * 64);
        }
        __syncthreads();
#pragma unroll
        for (int ks = 0; ks < 2; ks++) {
            const int ca = ks ? ca1 : ca0;
            short8 af[4], bf[4];
#pragma unroll
            for (int i = 0; i < 4; i++)
                af[i] = *reinterpret_cast<const short8*>(&As[(wm + i * 16 + lrow) * 64 + ca]);
#pragma unroll
            for (int j = 0; j < 4; j++)
                bf[j] = *reinterpret_cast<const short8*>(&Bs[(wn + j * 16 + lrow) * 64 + ca]);
#pragma unroll
            for (int i = 0; i < 4; i++)
#pragma unroll
                for (int j = 0; j < 4; j++)
                    acc[i][j] = __builtin_amdgcn_mfma_f32_16x16x32_bf16(af[i], bf[j], acc[i][j], 0, 0, 0);
        }
    }

#pragma unroll
    for (int i = 0; i < 4; i++) {
        int rb = m0 + wm + i * 16 + quad * 4;
#pragma unroll
        for (int j = 0; j < 4; j++) {
            int col = n0 + wn + j * 16 + lrow;
            float bv = bias[col];
#pragma unroll
            for (int r = 0; r < 4; r++) {
                size_t idx = (size_t)(rb + r) * N + col;
                float v = acc[i][j][r] + bv;
                if (EPI == 1) {
                    v += ((const float*)res)[idx];
                    ((unsigned short*)C)[idx] = f2b(v);
                } else {
                    v += b2f(((const unsigned short*)res)[idx]);
                    ((float*)C)[idx] = v;
                }
            }
        }
    }
}

// ---------------- fused QKV (BK=64 swizzled); Q pre-scaled; V -> per-head transposed Vt ----------------
__global__ __launch_bounds__(256, 3)
void gemm_qkv(const unsigned short* __restrict__ A, const unsigned short* __restrict__ Wqkv,
              const float* __restrict__ bq, const float* __restrict__ bk, const float* __restrict__ bv,
              unsigned short* __restrict__ QK, unsigned short* __restrict__ Vt)
{
    __shared__ unsigned short As[128 * 64];
    __shared__ unsigned short Bs[128 * 64];
    const int part = blockIdx.x >> 3;            // 0=Q 1=K 2=V
    const int m0 = blockIdx.y * 128, n0 = (blockIdx.x & 7) * 128;
    const int tid = threadIdx.x, wave = tid >> 6, lane = tid & 63;
    const int wm = (wave >> 1) * 64, wn = (wave & 1) * 64;
    const int lrow = lane & 15, quad = lane >> 4;
    const int srow = wave * 32 + (lane >> 3);
    const int scol = (((lane & 7) ^ ((lane >> 3) & 7)) << 3);
    const int ca0 = (quad ^ (lrow & 7)) << 3;
    const int ca1 = ((quad + 4) ^ (lrow & 7)) << 3;
    const unsigned short* B = Wqkv + (size_t)part * 1048576;
    const float* bias = (part == 0) ? bq : (part == 1) ? bk : bv;

    floatx4 acc[4][4] = {};
    const unsigned short* gA = A + (size_t)(m0 + srow) * 1024 + scol;
    const unsigned short* gB = B + (size_t)(n0 + srow) * 1024 + scol;
    unsigned short* lA = &As[(wave * 32) * 64];
    unsigned short* lB = &Bs[(wave * 32) * 64];

    for (int k0 = 0; k0 < 1024; k0 += 64) {
        __syncthreads();
#pragma unroll
        for (int r = 0; r < 4; r++) {
            async16(gA + k0 + (size_t)(r * 8) * 1024, lA + r * 8 * 64);
            async16(gB + k0 + (size_t)(r * 8) * 1024, lB + r * 8 * 64);
        }
        __syncthreads();
#pragma unroll
        for (int ks = 0; ks < 2; ks++) {
            const int ca = ks ? ca1 : ca0;
            short8 af[4], bf[4];
#pragma unroll
            for (int i = 0; i < 4; i++)
                af[i] = *reinterpret_cast<const short8*>(&As[(wm + i * 16 + lrow) * 64 + ca]);
#pragma unroll
            for (int j = 0; j < 4; j++)
                bf[j] = *reinterpret_cast<const short8*>(&Bs[(wn + j * 16 + lrow) * 64 + ca]);
#pragma unroll
            for (int i = 0; i < 4; i++)
#pragma unroll
                for (int j = 0; j < 4; j++)
                    acc[i][j] = __builtin_amdgcn_mfma_f32_16x16x32_bf16(af[i], bf[j], acc[i][j], 0, 0, 0);
        }
    }

#pragma unroll
    for (int i = 0; i < 4; i++) {
        int rb = m0 + wm + i * 16 + quad * 4;
#pragma unroll
        for (int j = 0; j < 4; j++) {
            int col = n0 + wn + j * 16 + lrow;
            float bv2 = bias[col];
            if (part == 0) {
#pragma unroll
                for (int r = 0; r < 4; r++)
                    QK[(size_t)(rb + r) * 1024 + col] = f2b((acc[i][j][r] + bv2) * EXP2_SCALE);
            } else if (part == 1) {
                unsigned short* dst = QK + 8388608;
#pragma unroll
                for (int r = 0; r < 4; r++)
                    dst[(size_t)(rb + r) * 1024 + col] = f2b(acc[i][j][r] + bv2);
            } else {
                int b = rb >> 11, spos = rb & 2047;
                int h = col >> 6, d = col & 63;
                unsigned short* dst = Vt + (((size_t)(b * 16 + h) * 64 + d) << 11) + spos;
                unsigned int u01 = pk_bf16(acc[i][j][0] + bv2, acc[i][j][1] + bv2);
                // round-to-nearest: use f2b for correctness parity with R5 (trunc vs rne negligible, keep rne)
                u01 = (unsigned int)f2b(acc[i][j][0] + bv2) | ((unsigned int)f2b(acc[i][j][1] + bv2) << 16);
                unsigned int u23 = (unsigned int)f2b(acc[i][j][2] + bv2) | ((unsigned int)f2b(acc[i][j][3] + bv2) << 16);
                *reinterpret_cast<uint2*>(dst) = make_uint2(u01, u23);
            }
        }
    }
}

// ---------------- Fused W1 + ReGLU (BK=64 swizzled) ----------------
__global__ __launch_bounds__(256, 2)
void gemm_w1_reglu(const unsigned short* __restrict__ A, const unsigned short* __restrict__ B,
                   const float* __restrict__ bias, unsigned short* __restrict__ G)
{
    __shared__ unsigned short As[128 * 64];
    __shared__ unsigned short B0s[128 * 64];
    __shared__ unsigned short B1s[128 * 64];
    const int m0 = blockIdx.y * 128, n0 = blockIdx.x * 128;  // n0 in [0,2048)
    const int tid = threadIdx.x, wave = tid >> 6, lane = tid & 63;
    const int wm = (wave >> 1) * 64, wn = (wave & 1) * 64;
    const int lrow = lane & 15, quad = lane >> 4;
    const int srow = wave * 32 + (lane >> 3);
    const int scol = (((lane & 7) ^ ((lane >> 3) & 7)) << 3);
    const int ca0 = (quad ^ (lrow & 7)) << 3;
    const int ca1 = ((quad + 4) ^ (lrow & 7)) << 3;

    floatx4 acca[4][4] = {};
    floatx4 accb[4][4] = {};
    const unsigned short* gA  = A + (size_t)(m0 + srow) * 1024 + scol;
    const unsigned short* gB0 = B + (size_t)(n0 + srow) * 1024 + scol;
    const unsigned short* gB1 = B + (size_t)(2048 + n0 + srow) * 1024 + scol;
    unsigned short* lA  = &As [(wave * 32) * 64];
    unsigned short* lB0 = &B0s[(wave * 32) * 64];
    unsigned short* lB1 = &B1s[(wave * 32) * 64];

    for (int k0 = 0; k0 < 1024; k0 += 64) {
        __syncthreads();
#pragma unroll
        for (int r = 0; r < 4; r++) {
            async16(gA  + k0 + (size_t)(r * 8) * 1024, lA  + r * 8 * 64);
            async16(gB0 + k0 + (size_t)(r * 8) * 1024, lB0 + r * 8 * 64);
            async16(gB1 + k0 + (size_t)(r * 8) * 1024, lB1 + r * 8 * 64);
        }
        __syncthreads();
#pragma unroll
        for (int ks = 0; ks < 2; ks++) {
            const int ca = ks ? ca1 : ca0;
            short8 af[4], b0[4], b1[4];
#pragma unroll
            for (int i = 0; i < 4; i++)
                af[i] = *reinterpret_cast<const short8*>(&As[(wm + i * 16 + lrow) * 64 + ca]);
#pragma unroll
            for (int j = 0; j < 4; j++) {
                b0[j] = *reinterpret_cast<const short8*>(&B0s[(wn + j * 16 + lrow) * 64 + ca]);
                b1[j] = *reinterpret_cast<const short8*>(&B1s[(wn + j * 16 + lrow) * 64 + ca]);
            }
#pragma unroll
            for (int i = 0; i < 4; i++)
#pragma unroll
                for (int j = 0; j < 4; j++) {
                    acca[i][j] = __builtin_amdgcn_mfma_f32_16x16x32_bf16(af[i], b0[j], acca[i][j], 0, 0, 0);
                    accb[i][j] = __builtin_amdgcn_mfma_f32_16x16x32_bf16(af[i], b1[j], accb[i][j], 0, 0, 0);
                }
        }
    }

#pragma unroll
    for (int i = 0; i < 4; i++) {
        int rb = m0 + wm + i * 16 + quad * 4;
#pragma unroll
        for (int j = 0; j < 4; j++) {
            int col = n0 + wn + j * 16 + lrow;
            float ba = bias[col], bb2 = bias[2048 + col];
#pragma unroll
            for (int r = 0; r < 4; r++) {
                float va = acca[i][j][r] + ba;
                float vb = accb[i][j][r] + bb2;
                G[(size_t)(rb + r) * 2048 + col] = f2b(fmaxf(va, 0.0f) * vb);
            }
        }
    }
}

// ---------------- Flash attention: S^T layout, occupancy 4 ----------------
__global__ __launch_bounds__(256, 4)
void attn_kernel(const unsigned short* __restrict__ Qm, const unsigned short* __restrict__ Km,
                 const unsigned short* __restrict__ Vt, unsigned short* __restrict__ ctx)
{
    __shared__ unsigned short Ks[64 * 64];      // [key][d], chunk-swizzled
    __shared__ unsigned short Vs[64 * 64];      // [d][key], chunk-swizzled
    __shared__ unsigned short Ps[4][32][72];    // per-wave P tile [qrow][key], padded

    const int tid = threadIdx.x, wave = tid >> 6, lane = tid & 63;
    const int lrow = lane & 15, quad = lane >> 4;
    const int qb = blockIdx.x, bh = blockIdx.y;
    const size_t base  = (size_t)(bh >> 4) * 2048 * 1024 + (size_t)(bh & 15) * 64;
    const size_t vbase = (size_t)bh * 131072;   // Vt head base [d][2048]
    const int q0 = qb * 128 + wave * 32;
    const int g_sub = (lane >> 3);
    const int g_col = (((lane & 7) ^ (g_sub & 7)) << 3);
    const int ca0 = (quad ^ (lrow & 7)) << 3;
    const int ca1 = ((quad + 4) ^ (lrow & 7)) << 3;

    short8 qf[2][2];
#pragma unroll
    for (int m = 0; m < 2; m++) {
        const unsigned short* qp = Qm + base + (size_t)(q0 + m * 16 + lrow) * 1024 + quad * 8;
        qf[m][0] = *reinterpret_cast<const short8*>(qp);
        qf[m][1] = *reinterpret_cast<const short8*>(qp + 32);
    }

    floatx4 o[2][4] = {};
    float li[2] = {0.f, 0.f};

    for (int t = 0; t < 32; t++) {
        const int k0 = t * 64;
        __syncthreads();
#pragma unroll
        for (int r = 0; r < 2; r++) {
            int krow = wave * 16 + r * 8 + g_sub;
            async16(Km + base + (size_t)(k0 + krow) * 1024 + g_col, &Ks[(wave * 16 + r * 8) * 64]);
            async16(Vt + vbase + (size_t)krow * 2048 + k0 + g_col,  &Vs[(wave * 16 + r * 8) * 64]);
        }
        __syncthreads();

        // S^T = K Q^T (Q pre-scaled by 0.125*log2e)
        short8 kf0[4], kf1[4];
#pragma unroll
        for (int j = 0; j < 4; j++) {
            kf0[j] = *reinterpret_cast<const short8*>(&Ks[(j * 16 + lrow) * 64 + ca0]);
            kf1[j] = *reinterpret_cast<const short8*>(&Ks[(j * 16 + lrow) * 64 + ca1]);
        }
        floatx4 s4t[2][4] = {};
#pragma unroll
        for (int m = 0; m < 2; m++)
#pragma unroll
            for (int j = 0; j < 4; j++) {
                s4t[m][j] = __builtin_amdgcn_mfma_f32_16x16x32_bf16(kf0[j], qf[m][0], s4t[m][j], 0, 0, 0);
                s4t[m][j] = __builtin_amdgcn_mfma_f32_16x16x32_bf16(kf1[j], qf[m][1], s4t[m][j], 0, 0, 0);
            }

        // p = exp2(s); per-lane scalar row partial; pack 4 keys -> one b64 write per (m,j)
#pragma unroll
        for (int m = 0; m < 2; m++) {
            float acc = 0.f;
#pragma unroll
            for (int j = 0; j < 4; j++) {
                float p0 = __builtin_amdgcn_exp2f(s4t[m][j][0]);
                float p1 = __builtin_amdgcn_exp2f(s4t[m][j][1]);
                float p2 = __builtin_amdgcn_exp2f(s4t[m][j][2]);
                float p3 = __builtin_amdgcn_exp2f(s4t[m][j][3]);
                acc += (p0 + p1) + (p2 + p3);
                uint2 pk = make_uint2(pk_bf16(p0, p1), pk_bf16(p2, p3));
                *reinterpret_cast<uint2*>(&Ps[wave][m * 16 + lrow][j * 16 + quad * 4]) = pk;
            }
            li[m] += acc;
        }
        __asm__ volatile("s_waitcnt lgkmcnt(0)" ::: "memory");  // wave-local P visibility

        // O += P V
        short8 pf[2][2];
#pragma unroll
        for (int m = 0; m < 2; m++) {
            pf[m][0] = *reinterpret_cast<const short8*>(&Ps[wave][m * 16 + lrow][quad * 8]);
            pf[m][1] = *reinterpret_cast<const short8*>(&Ps[wave][m * 16 + lrow][32 + quad * 8]);
        }
#pragma unroll
        for (int jj = 0; jj < 4; jj++) {
            short8 vf0 = *reinterpret_cast<const short8*>(&Vs[(jj * 16 + lrow) * 64 + ca0]);
            short8 vf1 = *reinterpret_cast<const short8*>(&Vs[(jj * 16 + lrow) * 64 + ca1]);
#pragma unroll
            for (int m = 0; m < 2; m++) {
                o[m][jj] = __builtin_amdgcn_mfma_f32_16x16x32_bf16(pf[m][0], vf0, o[m][jj], 0, 0, 0);
                o[m][jj] = __builtin_amdgcn_mfma_f32_16x16x32_bf16(pf[m][1], vf1, o[m][jj], 0, 0, 0);
            }
        }
    }

    // epilogue: row-sum across quads; per-row inv via shuffle
#pragma unroll
    for (int m = 0; m < 2; m++) {
        float l = li[m];
        l += __shfl_xor(l, 16, 64);
        l += __shfl_xor(l, 32, 64);
        float inv = 1.0f / l;
#pragma unroll
        for (int r = 0; r < 4; r++) {
            float invr = __shfl(inv, quad * 4 + r, 64);
            int srow = q0 + m * 16 + quad * 4 + r;
#pragma unroll
            for (int jj = 0; jj < 4; jj++)
                ctx[base + (size_t)srow * 1024 + jj * 16 + lrow] = f2b(o[m][jj][r] * invr);
        }
    }
}

extern "C" void kernel_launch(void* const* d_in, const int* in_sizes, int n_in,
                              void* d_out, int out_size, void* d_ws, size_t ws_size,
                              hipStream_t stream) {
    const float* x    = (const float*)d_in[0];
    const float* Wq   = (const float*)d_in[1];
    const float* bq   = (const float*)d_in[2];
    const float* Wk   = (const float*)d_in[3];
    const float* bk   = (const float*)d_in[4];
    const float* Wv   = (const float*)d_in[5];
    const float* bv   = (const float*)d_in[6];
    const float* Wo   = (const float*)d_in[7];
    const float* bo   = (const float*)d_in[8];
    const float* ln1g = (const float*)d_in[9];
    const float* ln1b = (const float*)d_in[10];
    const float* ln2g = (const float*)d_in[11];
    const float* ln2b = (const float*)d_in[12];
    const float* W1   = (const float*)d_in[13];
    const float* b1   = (const float*)d_in[14];
    const float* W2   = (const float*)d_in[15];
    const float* b2   = (const float*)d_in[16];
    float* out = (float*)d_out;

    char* ws = (char*)d_ws;
    // Workspace (100 MB peak):
    // [0,20MB)   bf16 weights flat: wq wk wv wo w1 w2
    // [20,36MB)  xn -> ctx -> xn2 (bf16 8192x1024)
    // [36,52MB)  Q   -> x1b (bf16 residual after attention)
    // [52,68MB)  K
    // [68,84MB)  Vt  }  g (bf16 8192x2048) overlays [68,100)
    unsigned short* wflat = (unsigned short*)ws;
    unsigned short* wqb = wflat;
    unsigned short* wob = wflat + 3145728;
    unsigned short* w1b = wflat + 4194304;
    unsigned short* w2b = wflat + 8388608;
    unsigned short* xn  = (unsigned short*)(ws + 20971520);
    unsigned short* Qm  = (unsigned short*)(ws + 37748736);
    unsigned short* x1b = (unsigned short*)(ws + 37748736);
    unsigned short* Vt  = (unsigned short*)(ws + 71303168);
    unsigned short* g   = (unsigned short*)(ws + 71303168);

    dim3 blk(256);
    // fused weight-cvt + LN1
    prep_kernel<<<13312, blk, 0, stream>>>(Wq, Wk, Wv, Wo, W1, W2, wflat, x, ln1g, ln1b, xn);
    gemm_qkv<<<dim3(24, 64), blk, 0, stream>>>(xn, wqb, bq, bk, bv, Qm, Vt);
    attn_kernel<<<dim3(16, 64), blk, 0, stream>>>(Qm, Qm + 8388608, Vt, xn);
    // Wo + residual(x fp32) -> x1b (bf16, overwrites Q region)
    gemm_nt<1><<<dim3(8, 64), blk, 0, stream>>>(xn, wob, bo, x, x1b, 8192, 1024, 1024);
    ln_kernel<<<8192, blk, 0, stream>>>(x1b, ln2g, ln2b, xn);
    gemm_w1_reglu<<<dim3(16, 64), blk, 0, stream>>>(xn, w1b, b1, g);
    // W2 + residual(x1b bf16) -> out fp32
    gemm_nt<2><<<dim3(8, 64), blk, 0, stream>>>(g, w2b, b2, x1b, out, 8192, 1024, 2048);
}